// Round 2
// 397.747 us; speedup vs baseline: 1.1175x; 1.1175x over previous
//
#include <hip/hip_runtime.h>
#include <stdint.h>

typedef __attribute__((ext_vector_type(8))) _Float16 half8;
typedef __attribute__((ext_vector_type(4))) _Float16 half4;
typedef __attribute__((ext_vector_type(4))) float f32x4;

// async global->LDS, 16B per lane; LDS dst must be wave-uniform base + lane*16
__device__ __forceinline__ void gload_lds16(const void* g, void* l) {
  __builtin_amdgcn_global_load_lds(
      (const __attribute__((address_space(1))) void*)g,
      (__attribute__((address_space(3))) void*)l, 16, 0, 0);
}

// C[M,N] = epilogue(A[M,K] @ Bt[N,K]^T + bias)   (A,Bt fp16; bias fp32)
// BK=64, XOR-swizzled LDS staging, DOUBLE-BUFFERED with raw s_barrier +
// s_waitcnt vmcnt(CHUNKS): next tile's global_load_lds stays in flight
// through the compute phase (AITER pattern; vmcnt never 0 mid-loop).
// Block ids are XCD-swizzled (chunked, bijective: all grids %8==0) so the
// col-blocks sharing an A-panel land on the same XCD's L2.
// EPI 0: leaky_relu(0.01) -> Ch fp16
// EPI 1: identity -> Cf fp32 (z out) AND Ch fp16 (z for VQ)
// EPI 2: sigmoid -> Cf fp32 (recon); accumulates sum((sig - Xref)^2), Xref fp16
template <int EPI, int BM, int BN>
__global__ __launch_bounds__(256, ((BM + BN) >= 256 ? 2 : ((BM + BN) == 192 ? 3 : 4)))
void gemm_bt(
    const _Float16* __restrict__ A, const _Float16* __restrict__ Bt,
    const float* __restrict__ bias, _Float16* __restrict__ Ch,
    float* __restrict__ Cf, int M, int N, int Kd,
    const _Float16* __restrict__ Xref, float* __restrict__ lossAcc) {
  constexpr int WM = BM / 2, WN = BN / 2;
  constexpr int MF = WM / 16, NF = WN / 16;
  constexpr int CA = BM / 32, CB = BN / 32;  // 16B staging chunks per thread
  constexpr int CHUNKS = CA + CB;
  constexpr int STAGE = (BM + BN) * 64;  // halfs per buffer
  __shared__ __align__(16) _Float16 smem[2 * STAGE];
  // scalar-reduction scratch lives past the epilogue eb region (64*BN floats)
  float* red = (float*)smem + 64 * BN;

  const int tid = threadIdx.x;
  const int lane = tid & 63;
  const int wav = tid >> 6;
  // XCD-aware chunked swizzle (bijective when nwg % 8 == 0)
  const int nx = gridDim.x;
  const int nwg = nx * (int)gridDim.y;
  int bid = (int)blockIdx.y * nx + (int)blockIdx.x;
  bid = (bid & 7) * (nwg >> 3) + (bid >> 3);
  const int shift = 31 - __clz(nx);  // nx is a power of two
  const int m0 = (bid >> shift) * BM;
  const int n0 = (bid & (nx - 1)) * BN;
  const int wm = (wav >> 1) * WM;
  const int wn = (wav & 1) * WN;
  const int l15 = lane & 15;
  const int quad = lane >> 4;

  f32x4 acc[MF][NF];
#pragma unroll
  for (int i = 0; i < MF; i++)
#pragma unroll
    for (int j = 0; j < NF; j++) acc[i][j] = (f32x4){0.f, 0.f, 0.f, 0.f};

  auto issue = [&](int kt, int b) {
    _Float16* As = smem + b * STAGE;
    _Float16* Bs = As + BM * 64;
#pragma unroll
    for (int j = 0; j < CA; j++) {
      const int ci = j * 256 + tid;
      const int row = ci >> 3;
      const int kc = ((ci & 7) ^ (row & 7)) << 3;
      gload_lds16(A + (size_t)(m0 + row) * Kd + kt + kc, &As[ci * 8]);
    }
#pragma unroll
    for (int j = 0; j < CB; j++) {
      const int ci = j * 256 + tid;
      const int row = ci >> 3;
      const int kc = ((ci & 7) ^ (row & 7)) << 3;
      gload_lds16(Bt + (size_t)(n0 + row) * Kd + kt + kc, &Bs[ci * 8]);
    }
  };

  int buf = 0;
  issue(0, 0);
  for (int kt = 0; kt < Kd; kt += 64) {
    if (kt + 64 < Kd) {
      issue(kt + 64, buf ^ 1);
      asm volatile("s_waitcnt vmcnt(%0)" ::"i"(CHUNKS) : "memory");
    } else {
      asm volatile("s_waitcnt vmcnt(0)" ::: "memory");
    }
    asm volatile("s_barrier" ::: "memory");

    const _Float16* As = smem + buf * STAGE;
    const _Float16* Bs = As + BM * 64;
#pragma unroll
    for (int s = 0; s < 2; s++) {
      half8 af[MF], bq[NF];
#pragma unroll
      for (int i = 0; i < MF; i++) {
        const int ra = wm + i * 16 + l15;
        const int ca = (s * 4 + quad) ^ (ra & 7);
        af[i] = *(const half8*)&As[ra * 64 + ca * 8];
      }
#pragma unroll
      for (int i = 0; i < NF; i++) {
        const int rb = wn + i * 16 + l15;
        const int cb = (s * 4 + quad) ^ (rb & 7);
        bq[i] = *(const half8*)&Bs[rb * 64 + cb * 8];
      }
#pragma unroll
      for (int mi = 0; mi < MF; mi++)
#pragma unroll
        for (int ni = 0; ni < NF; ni++)
          acc[mi][ni] = __builtin_amdgcn_mfma_f32_16x16x32_f16(af[mi], bq[ni],
                                                               acc[mi][ni], 0, 0, 0);
    }
    asm volatile("s_barrier" ::: "memory");  // protect buf^1 from next DMA
    buf ^= 1;
  }

  // epilogue: BM/64 phases of 64 rows through LDS (64 x BN fp32)
  float lsum = 0.f;
  float* eb = (float*)smem;
  constexpr int DIV = BN / 4;  // f32x4 cols
#pragma unroll
  for (int p = 0; p < BM / 64; p++) {
    __syncthreads();
    if ((wm >> 6) == p) {
#pragma unroll
      for (int mi = 0; mi < MF; mi++)
#pragma unroll
        for (int ni = 0; ni < NF; ni++)
#pragma unroll
          for (int r = 0; r < 4; r++) {
            const int rl = (wm & 63) + mi * 16 + quad * 4 + r;
            const int cl = wn + ni * 16 + l15;
            eb[rl * BN + cl] = acc[mi][ni][r];
          }
    }
    __syncthreads();
#pragma unroll
    for (int j = 0; j < BN / 16; j++) {
      const int c = j * 256 + tid;
      const int rl = c / DIV;
      const int cl = (c % DIV) * 4;
      const f32x4 v = *(const f32x4*)&eb[rl * BN + cl];
      const int gcol = n0 + cl;
      const f32x4 bv = *(const f32x4*)&bias[gcol];
      const size_t o = (size_t)(m0 + p * 64 + rl) * N + gcol;
      if (EPI == 0) {
        half4 h;
#pragma unroll
        for (int q = 0; q < 4; q++) {
          float t = v[q] + bv[q];
          t = t > 0.f ? t : 0.01f * t;
          h[q] = (_Float16)t;
        }
        *(half4*)&Ch[o] = h;
      } else if (EPI == 1) {
        f32x4 t;
        half4 h;
#pragma unroll
        for (int q = 0; q < 4; q++) {
          t[q] = v[q] + bv[q];
          h[q] = (_Float16)t[q];
        }
        *(f32x4*)&Cf[o] = t;
        *(half4*)&Ch[o] = h;
      } else {
        const half4 xr = *(const half4*)&Xref[o];
        f32x4 sv;
#pragma unroll
        for (int q = 0; q < 4; q++) {
          const float s = 1.f / (1.f + __expf(-(v[q] + bv[q])));
          sv[q] = s;
          const float d = s - (float)xr[q];
          lsum += d * d;
        }
        *(f32x4*)&Cf[o] = sv;
      }
    }
  }
  if (EPI == 2) {
    __syncthreads();
    red[tid] = lsum;
    __syncthreads();
    for (int s = 128; s > 0; s >>= 1) {
      if (tid < s) red[tid] += red[tid + s];
      __syncthreads();
    }
    if (tid == 0) atomicAdd(lossAcc, red[0]);
  }
}

// VQ: 128 rows/block, 32 rows/wave. Ehf holds -2*E in MFMA B-fragment order;
// dist = MFMA(z, -2E, C=e2); code index packed into low 11 mantissa bits of
// the fp32 dist key -> min-update is and+or+v_min_f32.
__global__ __launch_bounds__(256, 4) void vq_argmin(
    const _Float16* __restrict__ zh, const _Float16* __restrict__ Ehf,
    const float* __restrict__ E, const float* __restrict__ ek2,
    float* __restrict__ e_out, _Float16* __restrict__ eh_out,
    float* __restrict__ vq_acc) {
  __shared__ __align__(16) _Float16 Es[512 * 32];  // 512 codes, frag order (32 KB)
  __shared__ float ek2s[512];
  __shared__ float z2s[128];
  __shared__ int idxs[128];
  __shared__ float vred[256];

  const int tid = threadIdx.x;
  const int lane = tid & 63;
  const int wav = tid >> 6;
  const int l15 = lane & 15;
  const int quad = lane >> 4;
  const int rbase = blockIdx.x * 128 + wav * 32;
  constexpr unsigned KEYMASK = 0xFFFFF800u;

  half8 zf[2];
  float z2p[2];
#pragma unroll
  for (int m = 0; m < 2; m++) {
    zf[m] = *(const half8*)(zh + ((size_t)(rbase + m * 16 + l15)) * 32 + quad * 8);
    float s = 0.f;
#pragma unroll
    for (int j = 0; j < 8; j++) {
      float v = (float)zf[m][j];
      s += v * v;
    }
    s += __shfl_xor(s, 16);
    s += __shfl_xor(s, 32);
    z2p[m] = s;
  }
  if (quad == 0) {
#pragma unroll
    for (int m = 0; m < 2; m++) z2s[wav * 32 + m * 16 + l15] = z2p[m];
  }

  float key[2][4];
#pragma unroll
  for (int m = 0; m < 2; m++)
#pragma unroll
    for (int r = 0; r < 4; r++) key[m][r] = 1e30f;

  for (int cb = 0; cb < 2048; cb += 512) {
    __syncthreads();
#pragma unroll
    for (int j = 0; j < 8; j++) {
      const int u = j * 256 + tid;
      gload_lds16(Ehf + (size_t)cb * 32 + u * 8, &Es[u * 8]);
    }
    if (tid < 128) gload_lds16(&ek2[cb + tid * 4], &ek2s[tid * 4]);
    __syncthreads();

    int idxv = cb + l15;
    for (int c16 = 0; c16 < 32; c16++) {
      const half8 ef = *(const half8*)&Es[(c16 * 64 + lane) * 8];
      const float e2 = ek2s[c16 * 16 + l15];
      const f32x4 cinit = (f32x4){e2, e2, e2, e2};
      f32x4 d0 = __builtin_amdgcn_mfma_f32_16x16x32_f16(zf[0], ef, cinit, 0, 0, 0);
      f32x4 d1 = __builtin_amdgcn_mfma_f32_16x16x32_f16(zf[1], ef, cinit, 0, 0, 0);
#pragma unroll
      for (int r = 0; r < 4; r++) {
        key[0][r] = fminf(key[0][r],
                          __uint_as_float((__float_as_uint(d0[r]) & KEYMASK) | idxv));
        key[1][r] = fminf(key[1][r],
                          __uint_as_float((__float_as_uint(d1[r]) & KEYMASK) | idxv));
      }
      idxv += 16;
    }
  }

#pragma unroll
  for (int off = 1; off < 16; off <<= 1)
#pragma unroll
    for (int m = 0; m < 2; m++)
#pragma unroll
      for (int r = 0; r < 4; r++)
        key[m][r] = fminf(key[m][r], __shfl_xor(key[m][r], off));

  float vpart = 0.f;
  if (l15 == 0) {
#pragma unroll
    for (int m = 0; m < 2; m++)
#pragma unroll
      for (int r = 0; r < 4; r++) {
        const unsigned kb = __float_as_uint(key[m][r]);
        const int rl = wav * 32 + m * 16 + quad * 4 + r;
        idxs[rl] = (int)(kb & 0x7FFu);
        vpart += z2s[rl] + __uint_as_float(kb & KEYMASK);
      }
  }
  vred[tid] = vpart;
  __syncthreads();
  for (int s = 128; s > 0; s >>= 1) {
    if (tid < s) vred[tid] += vred[tid + s];
    __syncthreads();
  }
  if (tid == 0) atomicAdd(vq_acc, vred[0]);

  // gather e rows: 128 rows x 128B fp32; 4 threads/row, 2 iters
#pragma unroll
  for (int it = 0; it < 2; it++) {
    const int slot = it * 256 + tid;
    const int rowb = slot >> 2, part = slot & 3;
    const int idx = idxs[rowb];
    const size_t orow = ((size_t)blockIdx.x * 128 + rowb) * 32 + part * 8;
    const f32x4 ea = *(const f32x4*)(E + (size_t)idx * 32 + part * 8);
    const f32x4 ebv = *(const f32x4*)(E + (size_t)idx * 32 + part * 8 + 4);
    *(f32x4*)(e_out + orow) = ea;
    *(f32x4*)(e_out + orow + 4) = ebv;
    half8 ehv;
#pragma unroll
    for (int j = 0; j < 4; j++) {
      ehv[j] = (_Float16)ea[j];
      ehv[j + 4] = (_Float16)ebv[j];
    }
    *(half8*)(eh_out + orow) = ehv;
  }
}

// Fused preprocessing: conv_x (blocks [0,8192)) | 8 weight transposes
// ([8192, 8192+3456)) | conv_E (last 8 blocks).
struct PrepArgs {
  const float* W[8];
  _Float16* Wt[8];
  int Kw[8], Nw[8];
  int base[9];
  const float* x;
  _Float16* xh;
  const float* E;
  _Float16* Ehf;
  float* ek2;
};

__global__ __launch_bounds__(256) void prep_k(PrepArgs a) {
  __shared__ float t[32][33];
  const int b = blockIdx.x;
  const int tid = threadIdx.x;
  if (b < 8192) {  // x fp32 -> fp16, 8 elements/thread
    const size_t i = (size_t)b * 256 + tid;
    const f32x4 va = *(const f32x4*)(a.x + i * 8);
    const f32x4 vb = *(const f32x4*)(a.x + i * 8 + 4);
    half8 h;
#pragma unroll
    for (int j = 0; j < 4; j++) {
      h[j] = (_Float16)va[j];
      h[j + 4] = (_Float16)vb[j];
    }
    *(half8*)(a.xh + i * 8) = h;
    return;
  }
  if (b < 8192 + 3456) {  // W fp32 [K][N] -> Wt fp16 [N][K]
    int l = b - 8192;
    int w = 0;
    while (l >= a.base[w + 1]) w++;
    l -= a.base[w];
    const float* W = a.W[w];
    _Float16* Wt = a.Wt[w];
    const int K = a.Kw[w], N = a.Nw[w];
    const int nb = N >> 5;
    const int bx = (l % nb) * 32, by = (l / nb) * 32;
    const int tx = tid & 31, ty = tid >> 5;
#pragma unroll
    for (int i = 0; i < 32; i += 8)
      t[ty + i][tx] = W[(size_t)(by + ty + i) * N + bx + tx];
    __syncthreads();
#pragma unroll
    for (int i = 0; i < 32; i += 8)
      Wt[(size_t)(bx + ty + i) * K + by + tx] = (_Float16)t[tx][ty + i];
    return;
  }
  // conv_E: Ehf = -2*E fp16 in MFMA B-frag order + ek2 = ||E_c||^2
  const int c = (b - 8192 - 3456) * 256 + tid;
  float s = 0.f;
#pragma unroll
  for (int k = 0; k < 32; k++) {
    const float v = a.E[(size_t)c * 32 + k];
    s += v * v;
    a.Ehf[(size_t)((c >> 4) * 64 + (k >> 3) * 16 + (c & 15)) * 8 + (k & 7)] =
        (_Float16)(-2.f * v);
  }
  a.ek2[c] = s;
}

__global__ void finalize_k(const float* __restrict__ scal, float* __restrict__ out) {
  const float vq = 1.25f * (scal[0] / 16384.f);  // (1+BETA) * mean
  const float rl = scal[1] / 16384.f;
  out[0] = rl + vq;
  out[1] = rl;
  out[2] = vq;
}

extern "C" void kernel_launch(void* const* d_in, const int* in_sizes, int n_in,
                              void* d_out, int out_size, void* d_ws, size_t ws_size,
                              hipStream_t stream) {
  const float* x = (const float*)d_in[0];
  const float* be1 = (const float*)d_in[2];
  const float* be2 = (const float*)d_in[4];
  const float* be3 = (const float*)d_in[6];
  const float* be4 = (const float*)d_in[8];
  const float* E = (const float*)d_in[9];
  const float* bd1 = (const float*)d_in[11];
  const float* bd2 = (const float*)d_in[13];
  const float* bd3 = (const float*)d_in[15];
  const float* bd4 = (const float*)d_in[17];

  float* out = (float*)d_out;
  char* ws = (char*)d_ws;

  size_t off = 0;
  auto alloc = [&](size_t bytes) {
    size_t r = off;
    off += (bytes + 255) & ~(size_t)255;
    return r;
  };
  const size_t oXH = alloc((size_t)16384 * 1024 * 2);
  const size_t oWT1 = alloc((size_t)1024 * 1024 * 2);
  const size_t oWT2 = alloc((size_t)512 * 1024 * 2);
  const size_t oWT3 = alloc((size_t)256 * 512 * 2);
  const size_t oWT4 = alloc((size_t)256 * 256 * 2);
  const size_t oWD1 = alloc((size_t)256 * 256 * 2);
  const size_t oWD2 = alloc((size_t)512 * 256 * 2);
  const size_t oWD3 = alloc((size_t)1024 * 512 * 2);
  const size_t oWD4 = alloc((size_t)1024 * 1024 * 2);
  const size_t oEHF = alloc((size_t)2048 * 32 * 2);
  const size_t oEK2 = alloc((size_t)2048 * 4);
  const size_t oSC = alloc(256);
  const size_t oZH = alloc((size_t)16384 * 256 * 2);
  const size_t oQH = alloc((size_t)16384 * 256 * 2);
  const size_t oH1 = alloc((size_t)16384 * 1024 * 2);  // h1 / d3
  const size_t oH2 = alloc((size_t)16384 * 512 * 2);   // h2 / d2
  const size_t oH3 = alloc((size_t)16384 * 256 * 2);   // h3 / d1

  _Float16* xh = (_Float16*)(ws + oXH);
  _Float16* WT1 = (_Float16*)(ws + oWT1);
  _Float16* WT2 = (_Float16*)(ws + oWT2);
  _Float16* WT3 = (_Float16*)(ws + oWT3);
  _Float16* WT4 = (_Float16*)(ws + oWT4);
  _Float16* WD1 = (_Float16*)(ws + oWD1);
  _Float16* WD2 = (_Float16*)(ws + oWD2);
  _Float16* WD3 = (_Float16*)(ws + oWD3);
  _Float16* WD4 = (_Float16*)(ws + oWD4);
  _Float16* Ehf = (_Float16*)(ws + oEHF);
  float* ek2 = (float*)(ws + oEK2);
  float* scal = (float*)(ws + oSC);
  _Float16* zhw = (_Float16*)(ws + oZH);
  _Float16* qh = (_Float16*)(ws + oQH);
  _Float16* h1 = (_Float16*)(ws + oH1);
  _Float16* h2 = (_Float16*)(ws + oH2);
  _Float16* h3 = (_Float16*)(ws + oH3);

  float* zout = out;                            // [16384,256]
  float* eout = out + (size_t)16384 * 256;      // [16384,256]
  float* rout = out + (size_t)16384 * 256 * 2;  // [16384,1024]
  float* sout = rout + (size_t)16384 * 1024;    // 3 scalars

  hipMemsetAsync(ws + oSC, 0, 8, stream);

  PrepArgs pa;
  pa.W[0] = (const float*)d_in[1];  pa.Wt[0] = WT1; pa.Kw[0] = 1024; pa.Nw[0] = 1024;
  pa.W[1] = (const float*)d_in[3];  pa.Wt[1] = WT2; pa.Kw[1] = 1024; pa.Nw[1] = 512;
  pa.W[2] = (const float*)d_in[5];  pa.Wt[2] = WT3; pa.Kw[2] = 512;  pa.Nw[2] = 256;
  pa.W[3] = (const float*)d_in[7];  pa.Wt[3] = WT4; pa.Kw[3] = 256;  pa.Nw[3] = 256;
  pa.W[4] = (const float*)d_in[10]; pa.Wt[4] = WD1; pa.Kw[4] = 256;  pa.Nw[4] = 256;
  pa.W[5] = (const float*)d_in[12]; pa.Wt[5] = WD2; pa.Kw[5] = 256;  pa.Nw[5] = 512;
  pa.W[6] = (const float*)d_in[14]; pa.Wt[6] = WD3; pa.Kw[6] = 512;  pa.Nw[6] = 1024;
  pa.W[7] = (const float*)d_in[16]; pa.Wt[7] = WD4; pa.Kw[7] = 1024; pa.Nw[7] = 1024;
  int acc = 0;
  for (int w = 0; w < 8; w++) {
    pa.base[w] = acc;
    acc += (pa.Kw[w] >> 5) * (pa.Nw[w] >> 5);
  }
  pa.base[8] = acc;  // 3456
  pa.x = x; pa.xh = xh; pa.E = E; pa.Ehf = Ehf; pa.ek2 = ek2;

  dim3 blk(256);
  prep_k<<<8192 + 3456 + 8, blk, 0, stream>>>(pa);

  // encoder
  gemm_bt<0, 128, 128><<<dim3(8, 128), blk, 0, stream>>>(
      xh, WT1, be1, h1, nullptr, 16384, 1024, 1024, nullptr, nullptr);
  gemm_bt<0, 128, 128><<<dim3(4, 128), blk, 0, stream>>>(
      h1, WT2, be2, h2, nullptr, 16384, 512, 1024, nullptr, nullptr);
  gemm_bt<0, 64, 64><<<dim3(4, 256), blk, 0, stream>>>(
      h2, WT3, be3, h3, nullptr, 16384, 256, 512, nullptr, nullptr);
  gemm_bt<1, 64, 64><<<dim3(4, 256), blk, 0, stream>>>(
      h3, WT4, be4, zhw, zout, 16384, 256, 256, nullptr, nullptr);
  // vector quantizer
  vq_argmin<<<1024, blk, 0, stream>>>(zhw, Ehf, E, ek2, eout, qh, &scal[0]);
  // decoder
  gemm_bt<0, 64, 64><<<dim3(4, 256), blk, 0, stream>>>(
      qh, WD1, bd1, h3, nullptr, 16384, 256, 256, nullptr, nullptr);
  gemm_bt<0, 128, 128><<<dim3(4, 128), blk, 0, stream>>>(
      h3, WD2, bd2, h2, nullptr, 16384, 512, 256, nullptr, nullptr);
  gemm_bt<0, 128, 128><<<dim3(8, 128), blk, 0, stream>>>(
      h2, WD3, bd3, h1, nullptr, 16384, 1024, 512, nullptr, nullptr);
  gemm_bt<2, 128, 128><<<dim3(8, 128), blk, 0, stream>>>(
      h1, WD4, bd4, nullptr, rout, 16384, 1024, 1024, xh, &scal[1]);
  finalize_k<<<1, 1, 0, stream>>>(scal, sout);
}

// Round 3
// 381.709 us; speedup vs baseline: 1.1645x; 1.0420x over previous
//
#include <hip/hip_runtime.h>
#include <stdint.h>

typedef __attribute__((ext_vector_type(8))) _Float16 half8;
typedef __attribute__((ext_vector_type(4))) _Float16 half4;
typedef __attribute__((ext_vector_type(4))) float f32x4;

// async global->LDS, 16B per lane; LDS dst must be wave-uniform base + lane*16
__device__ __forceinline__ void gload_lds16(const void* g, void* l) {
  __builtin_amdgcn_global_load_lds(
      (const __attribute__((address_space(1))) void*)g,
      (__attribute__((address_space(3))) void*)l, 16, 0, 0);
}

#define GBAR asm volatile("s_barrier" ::: "memory")
#define LGKM0                                            \
  asm volatile("s_waitcnt lgkmcnt(0)" ::: "memory");     \
  __builtin_amdgcn_sched_barrier(0)

// ---------------------------------------------------------------------------
// 8-phase 256x256 GEMM (T3+T4+T5): C = epi(A[M,K] @ Bt[N,K]^T + bias).
// 512 thr = 8 waves (2M x 4N), per-wave 128x64. BK=64. Dynamic LDS 128 KB =
// 2 slots x (A 32K | B 32K). Per K-tile quad: 4 phases, quadrant gray order
// (0,0)(0,1)(1,1)(1,0); each phase: ds_reads, issue ONE half-tile prefetch
// (2 x gload_lds) into a dead region, barrier, lgkmcnt(0), 16 MFMA under
// setprio(1), barrier. vmcnt(4) once per quad (2 half-tiles stay in flight).
// LDS rows permuted so each half-tile is contiguous: A row = qm*128+wr*64+lo,
// B row = qn*128+wc*32+lo. k-chunk XOR-swizzled by (row&7) on BOTH sides.
// EPI 0: leaky_relu -> Ch fp16.  EPI 2: sigmoid -> Cf fp32 + loss vs Xref.
// ---------------------------------------------------------------------------
#define MMA_Q(QM, QN)                                                        \
  __builtin_amdgcn_s_setprio(1);                                             \
  _Pragma("unroll") for (int s = 0; s < 2; s++)                              \
  _Pragma("unroll") for (int i = 0; i < 4; i++)                              \
  _Pragma("unroll") for (int j = 0; j < 2; j++)                              \
      acc[(QM) * 4 + i][(QN) * 2 + j] = __builtin_amdgcn_mfma_f32_16x16x32_f16( \
          af[i][s], bq[j][s], acc[(QM) * 4 + i][(QN) * 2 + j], 0, 0, 0);     \
  __builtin_amdgcn_s_setprio(0);

template <int EPI>
__global__ __launch_bounds__(512, 2) void gemm8p(
    const _Float16* __restrict__ A, const _Float16* __restrict__ Bt,
    const float* __restrict__ bias, _Float16* __restrict__ Ch,
    float* __restrict__ Cf, int M, int N, int Kd,
    const _Float16* __restrict__ Xref, float* __restrict__ lossAcc) {
  extern __shared__ __align__(16) char dyn[];

  const int tid = threadIdx.x;
  const int lane = tid & 63;
  const int wav = tid >> 6;  // 0..7
  const int wr = wav >> 2;   // 0..1 (M half)
  const int wc = wav & 3;    // 0..3 (N quarter)
  const int l15 = lane & 15;
  const int quad = lane >> 4;

  // XCD-aware chunked swizzle (nwg = 256, bijective)
  const int nx = gridDim.x;
  const int nwg = nx * (int)gridDim.y;
  int bid = (int)blockIdx.y * nx + (int)blockIdx.x;
  bid = (bid & 7) * (nwg >> 3) + (bid >> 3);
  const int shift = 31 - __clz(nx);
  const int m0 = (bid >> shift) * 256;
  const int n0 = (bid & (nx - 1)) * 256;

  f32x4 acc[8][4];
#pragma unroll
  for (int i = 0; i < 8; i++)
#pragma unroll
    for (int j = 0; j < 4; j++) acc[i][j] = (f32x4){0.f, 0.f, 0.f, 0.f};

  // stage one 64-LDS-row block (8 KB = 512 thr x 16B), RB in {0,64,128,192}
  auto stageA = [&](int kt, int slot, int RB) {
    const int row = RB + (tid >> 3);
    const int ch = tid & 7;
    const int gm = m0 + ((row >> 6) & 1) * 128 + (row >> 7) * 64 + (row & 63);
    const int kc = (ch ^ (row & 7)) << 3;
    gload_lds16(A + (size_t)gm * Kd + kt + kc,
                dyn + slot * 65536 + row * 128 + ch * 16);
  };
  auto stageB = [&](int kt, int slot, int RB) {
    const int row = RB + (tid >> 3);
    const int ch = tid & 7;
    const int gn = n0 + ((row >> 5) & 3) * 64 + (row >> 7) * 32 + (row & 31);
    const int kc = (ch ^ (row & 7)) << 3;
    gload_lds16(Bt + (size_t)gn * Kd + kt + kc,
                dyn + slot * 65536 + 32768 + row * 128 + ch * 16);
  };

  half8 af[4][2], bq[2][2];
  auto dsA = [&](const _Float16* As, int qm) {
#pragma unroll
    for (int i = 0; i < 4; i++) {
      const int ra = qm * 128 + wr * 64 + i * 16 + l15;
#pragma unroll
      for (int s = 0; s < 2; s++)
        af[i][s] = *(const half8*)&As[ra * 64 + (((s * 4 + quad) ^ (ra & 7)) << 3)];
    }
  };
  auto dsB = [&](const _Float16* Bs, int qn) {
#pragma unroll
    for (int j = 0; j < 2; j++) {
      const int rb = qn * 128 + wc * 32 + j * 16 + l15;
#pragma unroll
      for (int s = 0; s < 2; s++)
        bq[j][s] = *(const half8*)&Bs[rb * 64 + (((s * 4 + quad) ^ (rb & 7)) << 3)];
    }
  };

  const int NT = Kd >> 6;  // >= 8 for all users

  // prologue: tile0 complete + Aalpha/Bbeta of tile1; then vmcnt(4) leaves
  // exactly those 2 half-tiles (4 loads) in flight.
  stageA(0, 0, 0);
  stageA(0, 0, 64);  // Aalpha(0)
  stageB(0, 0, 128);
  stageB(0, 0, 192);  // Bbeta(0)
  stageA(0, 0, 128);
  stageA(0, 0, 192);  // Abeta(0)
  stageB(0, 0, 0);
  stageB(0, 0, 64);  // Balpha(0)
  stageA(64, 1, 0);
  stageA(64, 1, 64);  // Aalpha(1)
  stageB(64, 1, 128);
  stageB(64, 1, 192);  // Bbeta(1)
  asm volatile("s_waitcnt vmcnt(4)" ::: "memory");
  GBAR;

  for (int t = 0; t < NT; ++t) {
    const int slot = t & 1;
    const int nsl = slot ^ 1;
    const int kt1 = (t + 1) << 6;
    const int kt2 = (t + 2) << 6;
    const bool p1 = (t + 1) < NT;
    const bool p2 = (t + 2) < NT;
    const _Float16* As = (const _Float16*)(dyn + slot * 65536);
    const _Float16* Bs = (const _Float16*)(dyn + slot * 65536 + 32768);

    // ph1 (qm0,qn0): Aalpha/Balpha last ds_read of this tile's regions
    dsA(As, 0);
    dsB(Bs, 0);
    if (p1) { stageA(kt1, nsl, 128); stageA(kt1, nsl, 192); }  // Abeta(t+1)
    GBAR;
    LGKM0;
    MMA_Q(0, 0);
    GBAR;
    // ph2 (0,1)
    dsB(Bs, 1);
    if (p1) { stageB(kt1, nsl, 0); stageB(kt1, nsl, 64); }  // Balpha(t+1)
    GBAR;
    LGKM0;
    MMA_Q(0, 1);
    GBAR;
    // ph3 (1,1): Aalpha(t) dead since ph1 -> stage Aalpha(t+2) over it
    dsA(As, 1);
    if (p2) { stageA(kt2, slot, 0); stageA(kt2, slot, 64); }  // Aalpha(t+2)
    GBAR;
    LGKM0;
    MMA_Q(1, 1);
    GBAR;
    // ph4 (1,0): Bbeta(t) dead since ph2 -> stage Bbeta(t+2) over it
    dsB(Bs, 0);
    if (p2) { stageB(kt2, slot, 128); stageB(kt2, slot, 192); }  // Bbeta(t+2)
    GBAR;
    LGKM0;
    MMA_Q(1, 0);
    if (p2) {
      asm volatile("s_waitcnt vmcnt(4)" ::: "memory");
    } else {
      asm volatile("s_waitcnt vmcnt(0)" ::: "memory");
    }
    GBAR;
  }

  // epilogue: 4 phases of 64 rows x 256 cols fp32 through LDS
  float lsum = 0.f;
  float* eb = (float*)dyn;
  float* red = (float*)dyn + 64 * 256;
#pragma unroll
  for (int p = 0; p < 4; p++) {
    __syncthreads();
    if (wr == (p >> 1)) {
#pragma unroll
      for (int mi2 = 0; mi2 < 4; mi2++) {
        const int mi = (p & 1) * 4 + mi2;
#pragma unroll
        for (int ni = 0; ni < 4; ni++)
#pragma unroll
          for (int r = 0; r < 4; r++) {
            const int rl = mi2 * 16 + quad * 4 + r;
            const int cl = wc * 64 + ni * 16 + l15;
            eb[rl * 256 + cl] = acc[mi][ni][r];
          }
      }
    }
    __syncthreads();
#pragma unroll
    for (int j = 0; j < 8; j++) {
      const int c = j * 512 + tid;
      const int rl = c >> 6;
      const int cl = (c & 63) * 4;
      const f32x4 v = *(const f32x4*)&eb[rl * 256 + cl];
      const int gcol = n0 + cl;
      const f32x4 bv = *(const f32x4*)&bias[gcol];
      const size_t o = (size_t)(m0 + p * 64 + rl) * N + gcol;
      if (EPI == 0) {
        half4 h;
#pragma unroll
        for (int q = 0; q < 4; q++) {
          float tv = v[q] + bv[q];
          tv = tv > 0.f ? tv : 0.01f * tv;
          h[q] = (_Float16)tv;
        }
        *(half4*)&Ch[o] = h;
      } else {
        const half4 xr = *(const half4*)&Xref[o];
        f32x4 sv;
#pragma unroll
        for (int q = 0; q < 4; q++) {
          const float sg = 1.f / (1.f + __expf(-(v[q] + bv[q])));
          sv[q] = sg;
          const float d = sg - (float)xr[q];
          lsum += d * d;
        }
        *(f32x4*)&Cf[o] = sv;
      }
    }
  }
  if (EPI == 2) {
    __syncthreads();
    red[tid] = lsum;
    __syncthreads();
    for (int s = 256; s > 0; s >>= 1) {
      if (tid < s) red[tid] += red[tid + s];
      __syncthreads();
    }
    if (tid == 0) atomicAdd(lossAcc, red[0]);
  }
}

// ---------------------------------------------------------------------------
// 2-phase kernel (verified) — kept for the small/narrow layers.
// ---------------------------------------------------------------------------
template <int EPI, int BM, int BN>
__global__ __launch_bounds__(256, ((BM + BN) >= 256 ? 2 : ((BM + BN) == 192 ? 3 : 4)))
void gemm_bt(
    const _Float16* __restrict__ A, const _Float16* __restrict__ Bt,
    const float* __restrict__ bias, _Float16* __restrict__ Ch,
    float* __restrict__ Cf, int M, int N, int Kd,
    const _Float16* __restrict__ Xref, float* __restrict__ lossAcc) {
  constexpr int WM = BM / 2, WN = BN / 2;
  constexpr int MF = WM / 16, NF = WN / 16;
  constexpr int CA = BM / 32, CB = BN / 32;
  constexpr int CHUNKS = CA + CB;
  constexpr int STAGE = (BM + BN) * 64;
  __shared__ __align__(16) _Float16 smem[2 * STAGE];
  float* red = (float*)smem + 64 * BN;

  const int tid = threadIdx.x;
  const int lane = tid & 63;
  const int wav = tid >> 6;
  const int nx = gridDim.x;
  const int nwg = nx * (int)gridDim.y;
  int bid = (int)blockIdx.y * nx + (int)blockIdx.x;
  bid = (bid & 7) * (nwg >> 3) + (bid >> 3);
  const int shift = 31 - __clz(nx);
  const int m0 = (bid >> shift) * BM;
  const int n0 = (bid & (nx - 1)) * BN;
  const int wm = (wav >> 1) * WM;
  const int wn = (wav & 1) * WN;
  const int l15 = lane & 15;
  const int quad = lane >> 4;

  f32x4 acc[MF][NF];
#pragma unroll
  for (int i = 0; i < MF; i++)
#pragma unroll
    for (int j = 0; j < NF; j++) acc[i][j] = (f32x4){0.f, 0.f, 0.f, 0.f};

  auto issue = [&](int kt, int b) {
    _Float16* As = smem + b * STAGE;
    _Float16* Bs = As + BM * 64;
#pragma unroll
    for (int j = 0; j < CA; j++) {
      const int ci = j * 256 + tid;
      const int row = ci >> 3;
      const int kc = ((ci & 7) ^ (row & 7)) << 3;
      gload_lds16(A + (size_t)(m0 + row) * Kd + kt + kc, &As[ci * 8]);
    }
#pragma unroll
    for (int j = 0; j < CB; j++) {
      const int ci = j * 256 + tid;
      const int row = ci >> 3;
      const int kc = ((ci & 7) ^ (row & 7)) << 3;
      gload_lds16(Bt + (size_t)(n0 + row) * Kd + kt + kc, &Bs[ci * 8]);
    }
  };

  int buf = 0;
  issue(0, 0);
  for (int kt = 0; kt < Kd; kt += 64) {
    if (kt + 64 < Kd) {
      issue(kt + 64, buf ^ 1);
      asm volatile("s_waitcnt vmcnt(%0)" ::"i"(CHUNKS) : "memory");
    } else {
      asm volatile("s_waitcnt vmcnt(0)" ::: "memory");
    }
    asm volatile("s_barrier" ::: "memory");

    const _Float16* As = smem + buf * STAGE;
    const _Float16* Bs = As + BM * 64;
#pragma unroll
    for (int s = 0; s < 2; s++) {
      half8 af[MF], bqv[NF];
#pragma unroll
      for (int i = 0; i < MF; i++) {
        const int ra = wm + i * 16 + l15;
        const int ca = (s * 4 + quad) ^ (ra & 7);
        af[i] = *(const half8*)&As[ra * 64 + ca * 8];
      }
#pragma unroll
      for (int i = 0; i < NF; i++) {
        const int rb = wn + i * 16 + l15;
        const int cb = (s * 4 + quad) ^ (rb & 7);
        bqv[i] = *(const half8*)&Bs[rb * 64 + cb * 8];
      }
#pragma unroll
      for (int mi = 0; mi < MF; mi++)
#pragma unroll
        for (int ni = 0; ni < NF; ni++)
          acc[mi][ni] = __builtin_amdgcn_mfma_f32_16x16x32_f16(af[mi], bqv[ni],
                                                               acc[mi][ni], 0, 0, 0);
    }
    asm volatile("s_barrier" ::: "memory");
    buf ^= 1;
  }

  float lsum = 0.f;
  float* eb = (float*)smem;
  constexpr int DIV = BN / 4;
#pragma unroll
  for (int p = 0; p < BM / 64; p++) {
    __syncthreads();
    if ((wm >> 6) == p) {
#pragma unroll
      for (int mi = 0; mi < MF; mi++)
#pragma unroll
        for (int ni = 0; ni < NF; ni++)
#pragma unroll
          for (int r = 0; r < 4; r++) {
            const int rl = (wm & 63) + mi * 16 + quad * 4 + r;
            const int cl = wn + ni * 16 + l15;
            eb[rl * BN + cl] = acc[mi][ni][r];
          }
    }
    __syncthreads();
#pragma unroll
    for (int j = 0; j < BN / 16; j++) {
      const int c = j * 256 + tid;
      const int rl = c / DIV;
      const int cl = (c % DIV) * 4;
      const f32x4 v = *(const f32x4*)&eb[rl * BN + cl];
      const int gcol = n0 + cl;
      const f32x4 bv = *(const f32x4*)&bias[gcol];
      const size_t o = (size_t)(m0 + p * 64 + rl) * N + gcol;
      if (EPI == 0) {
        half4 h;
#pragma unroll
        for (int q = 0; q < 4; q++) {
          float t = v[q] + bv[q];
          t = t > 0.f ? t : 0.01f * t;
          h[q] = (_Float16)t;
        }
        *(half4*)&Ch[o] = h;
      } else if (EPI == 1) {
        f32x4 t;
        half4 h;
#pragma unroll
        for (int q = 0; q < 4; q++) {
          t[q] = v[q] + bv[q];
          h[q] = (_Float16)t[q];
        }
        *(f32x4*)&Cf[o] = t;
        *(half4*)&Ch[o] = h;
      } else {
        const half4 xr = *(const half4*)&Xref[o];
        f32x4 sv;
#pragma unroll
        for (int q = 0; q < 4; q++) {
          const float s = 1.f / (1.f + __expf(-(v[q] + bv[q])));
          sv[q] = s;
          const float d = s - (float)xr[q];
          lsum += d * d;
        }
        *(f32x4*)&Cf[o] = sv;
      }
    }
  }
  if (EPI == 2) {
    __syncthreads();
    red[tid] = lsum;
    __syncthreads();
    for (int s = 128; s > 0; s >>= 1) {
      if (tid < s) red[tid] += red[tid + s];
      __syncthreads();
    }
    if (tid == 0) atomicAdd(lossAcc, red[0]);
  }
}

// VQ: 128 rows/block, 32 rows/wave. Ehf holds -2*E in MFMA B-fragment order;
// dist = MFMA(z, -2E, C=e2); code index packed into low 11 mantissa bits of
// the fp32 dist key -> min-update is and+or+v_min_f32.
__global__ __launch_bounds__(256, 4) void vq_argmin(
    const _Float16* __restrict__ zh, const _Float16* __restrict__ Ehf,
    const float* __restrict__ E, const float* __restrict__ ek2,
    float* __restrict__ e_out, _Float16* __restrict__ eh_out,
    float* __restrict__ vq_acc) {
  __shared__ __align__(16) _Float16 Es[512 * 32];
  __shared__ float ek2s[512];
  __shared__ float z2s[128];
  __shared__ int idxs[128];
  __shared__ float vred[256];

  const int tid = threadIdx.x;
  const int lane = tid & 63;
  const int wav = tid >> 6;
  const int l15 = lane & 15;
  const int quad = lane >> 4;
  const int rbase = blockIdx.x * 128 + wav * 32;
  constexpr unsigned KEYMASK = 0xFFFFF800u;

  half8 zf[2];
  float z2p[2];
#pragma unroll
  for (int m = 0; m < 2; m++) {
    zf[m] = *(const half8*)(zh + ((size_t)(rbase + m * 16 + l15)) * 32 + quad * 8);
    float s = 0.f;
#pragma unroll
    for (int j = 0; j < 8; j++) {
      float v = (float)zf[m][j];
      s += v * v;
    }
    s += __shfl_xor(s, 16);
    s += __shfl_xor(s, 32);
    z2p[m] = s;
  }
  if (quad == 0) {
#pragma unroll
    for (int m = 0; m < 2; m++) z2s[wav * 32 + m * 16 + l15] = z2p[m];
  }

  float key[2][4];
#pragma unroll
  for (int m = 0; m < 2; m++)
#pragma unroll
    for (int r = 0; r < 4; r++) key[m][r] = 1e30f;

  for (int cb = 0; cb < 2048; cb += 512) {
    __syncthreads();
#pragma unroll
    for (int j = 0; j < 8; j++) {
      const int u = j * 256 + tid;
      gload_lds16(Ehf + (size_t)cb * 32 + u * 8, &Es[u * 8]);
    }
    if (tid < 128) gload_lds16(&ek2[cb + tid * 4], &ek2s[tid * 4]);
    __syncthreads();

    int idxv = cb + l15;
    for (int c16 = 0; c16 < 32; c16++) {
      const half8 ef = *(const half8*)&Es[(c16 * 64 + lane) * 8];
      const float e2 = ek2s[c16 * 16 + l15];
      const f32x4 cinit = (f32x4){e2, e2, e2, e2};
      f32x4 d0 = __builtin_amdgcn_mfma_f32_16x16x32_f16(zf[0], ef, cinit, 0, 0, 0);
      f32x4 d1 = __builtin_amdgcn_mfma_f32_16x16x32_f16(zf[1], ef, cinit, 0, 0, 0);
#pragma unroll
      for (int r = 0; r < 4; r++) {
        key[0][r] = fminf(key[0][r],
                          __uint_as_float((__float_as_uint(d0[r]) & KEYMASK) | idxv));
        key[1][r] = fminf(key[1][r],
                          __uint_as_float((__float_as_uint(d1[r]) & KEYMASK) | idxv));
      }
      idxv += 16;
    }
  }

#pragma unroll
  for (int off = 1; off < 16; off <<= 1)
#pragma unroll
    for (int m = 0; m < 2; m++)
#pragma unroll
      for (int r = 0; r < 4; r++)
        key[m][r] = fminf(key[m][r], __shfl_xor(key[m][r], off));

  float vpart = 0.f;
  if (l15 == 0) {
#pragma unroll
    for (int m = 0; m < 2; m++)
#pragma unroll
      for (int r = 0; r < 4; r++) {
        const unsigned kb = __float_as_uint(key[m][r]);
        const int rl = wav * 32 + m * 16 + quad * 4 + r;
        idxs[rl] = (int)(kb & 0x7FFu);
        vpart += z2s[rl] + __uint_as_float(kb & KEYMASK);
      }
  }
  vred[tid] = vpart;
  __syncthreads();
  for (int s = 128; s > 0; s >>= 1) {
    if (tid < s) vred[tid] += vred[tid + s];
    __syncthreads();
  }
  if (tid == 0) atomicAdd(vq_acc, vred[0]);

#pragma unroll
  for (int it = 0; it < 2; it++) {
    const int slot = it * 256 + tid;
    const int rowb = slot >> 2, part = slot & 3;
    const int idx = idxs[rowb];
    const size_t orow = ((size_t)blockIdx.x * 128 + rowb) * 32 + part * 8;
    const f32x4 ea = *(const f32x4*)(E + (size_t)idx * 32 + part * 8);
    const f32x4 ebv = *(const f32x4*)(E + (size_t)idx * 32 + part * 8 + 4);
    *(f32x4*)(e_out + orow) = ea;
    *(f32x4*)(e_out + orow + 4) = ebv;
    half8 ehv;
#pragma unroll
    for (int j = 0; j < 4; j++) {
      ehv[j] = (_Float16)ea[j];
      ehv[j + 4] = (_Float16)ebv[j];
    }
    *(half8*)(eh_out + orow) = ehv;
  }
}

// Fused preprocessing: conv_x (blocks [0,8192)) | 8 weight transposes
// ([8192, 8192+3456)) | conv_E (last 8 blocks).
struct PrepArgs {
  const float* W[8];
  _Float16* Wt[8];
  int Kw[8], Nw[8];
  int base[9];
  const float* x;
  _Float16* xh;
  const float* E;
  _Float16* Ehf;
  float* ek2;
};

__global__ __launch_bounds__(256) void prep_k(PrepArgs a) {
  __shared__ float t[32][33];
  const int b = blockIdx.x;
  const int tid = threadIdx.x;
  if (b < 8192) {
    const size_t i = (size_t)b * 256 + tid;
    const f32x4 va = *(const f32x4*)(a.x + i * 8);
    const f32x4 vb = *(const f32x4*)(a.x + i * 8 + 4);
    half8 h;
#pragma unroll
    for (int j = 0; j < 4; j++) {
      h[j] = (_Float16)va[j];
      h[j + 4] = (_Float16)vb[j];
    }
    *(half8*)(a.xh + i * 8) = h;
    return;
  }
  if (b < 8192 + 3456) {
    int l = b - 8192;
    int w = 0;
    while (l >= a.base[w + 1]) w++;
    l -= a.base[w];
    const float* W = a.W[w];
    _Float16* Wt = a.Wt[w];
    const int K = a.Kw[w], N = a.Nw[w];
    const int nb = N >> 5;
    const int bx = (l % nb) * 32, by = (l / nb) * 32;
    const int tx = tid & 31, ty = tid >> 5;
#pragma unroll
    for (int i = 0; i < 32; i += 8)
      t[ty + i][tx] = W[(size_t)(by + ty + i) * N + bx + tx];
    __syncthreads();
#pragma unroll
    for (int i = 0; i < 32; i += 8)
      Wt[(size_t)(bx + ty + i) * K + by + tx] = (_Float16)t[tx][ty + i];
    return;
  }
  const int c = (b - 8192 - 3456) * 256 + tid;
  float s = 0.f;
#pragma unroll
  for (int k = 0; k < 32; k++) {
    const float v = a.E[(size_t)c * 32 + k];
    s += v * v;
    a.Ehf[(size_t)((c >> 4) * 64 + (k >> 3) * 16 + (c & 15)) * 8 + (k & 7)] =
        (_Float16)(-2.f * v);
  }
  a.ek2[c] = s;
}

__global__ void finalize_k(const float* __restrict__ scal, float* __restrict__ out) {
  const float vq = 1.25f * (scal[0] / 16384.f);
  const float rl = scal[1] / 16384.f;
  out[0] = rl + vq;
  out[1] = rl;
  out[2] = vq;
}

extern "C" void kernel_launch(void* const* d_in, const int* in_sizes, int n_in,
                              void* d_out, int out_size, void* d_ws, size_t ws_size,
                              hipStream_t stream) {
  const float* x = (const float*)d_in[0];
  const float* be1 = (const float*)d_in[2];
  const float* be2 = (const float*)d_in[4];
  const float* be3 = (const float*)d_in[6];
  const float* be4 = (const float*)d_in[8];
  const float* E = (const float*)d_in[9];
  const float* bd1 = (const float*)d_in[11];
  const float* bd2 = (const float*)d_in[13];
  const float* bd3 = (const float*)d_in[15];
  const float* bd4 = (const float*)d_in[17];

  float* out = (float*)d_out;
  char* ws = (char*)d_ws;

  size_t off = 0;
  auto alloc = [&](size_t bytes) {
    size_t r = off;
    off += (bytes + 255) & ~(size_t)255;
    return r;
  };
  const size_t oXH = alloc((size_t)16384 * 1024 * 2);
  const size_t oWT1 = alloc((size_t)1024 * 1024 * 2);
  const size_t oWT2 = alloc((size_t)512 * 1024 * 2);
  const size_t oWT3 = alloc((size_t)256 * 512 * 2);
  const size_t oWT4 = alloc((size_t)256 * 256 * 2);
  const size_t oWD1 = alloc((size_t)256 * 256 * 2);
  const size_t oWD2 = alloc((size_t)512 * 256 * 2);
  const size_t oWD3 = alloc((size_t)1024 * 512 * 2);
  const size_t oWD4 = alloc((size_t)1024 * 1024 * 2);
  const size_t oEHF = alloc((size_t)2048 * 32 * 2);
  const size_t oEK2 = alloc((size_t)2048 * 4);
  const size_t oSC = alloc(256);
  const size_t oZH = alloc((size_t)16384 * 256 * 2);
  const size_t oQH = alloc((size_t)16384 * 256 * 2);
  const size_t oH1 = alloc((size_t)16384 * 1024 * 2);
  const size_t oH2 = alloc((size_t)16384 * 512 * 2);
  const size_t oH3 = alloc((size_t)16384 * 256 * 2);

  _Float16* xh = (_Float16*)(ws + oXH);
  _Float16* WT1 = (_Float16*)(ws + oWT1);
  _Float16* WT2 = (_Float16*)(ws + oWT2);
  _Float16* WT3 = (_Float16*)(ws + oWT3);
  _Float16* WT4 = (_Float16*)(ws + oWT4);
  _Float16* WD1 = (_Float16*)(ws + oWD1);
  _Float16* WD2 = (_Float16*)(ws + oWD2);
  _Float16* WD3 = (_Float16*)(ws + oWD3);
  _Float16* WD4 = (_Float16*)(ws + oWD4);
  _Float16* Ehf = (_Float16*)(ws + oEHF);
  float* ek2 = (float*)(ws + oEK2);
  float* scal = (float*)(ws + oSC);
  _Float16* zhw = (_Float16*)(ws + oZH);
  _Float16* qh = (_Float16*)(ws + oQH);
  _Float16* h1 = (_Float16*)(ws + oH1);
  _Float16* h2 = (_Float16*)(ws + oH2);
  _Float16* h3 = (_Float16*)(ws + oH3);

  float* zout = out;
  float* eout = out + (size_t)16384 * 256;
  float* rout = out + (size_t)16384 * 256 * 2;
  float* sout = rout + (size_t)16384 * 1024;

  hipMemsetAsync(ws + oSC, 0, 8, stream);

  // allow 128 KB dynamic LDS for the 8-phase kernels (idempotent host call)
  hipFuncSetAttribute((const void*)gemm8p<0>,
                      hipFuncAttributeMaxDynamicSharedMemorySize, 131072);
  hipFuncSetAttribute((const void*)gemm8p<2>,
                      hipFuncAttributeMaxDynamicSharedMemorySize, 131072);

  PrepArgs pa;
  pa.W[0] = (const float*)d_in[1];  pa.Wt[0] = WT1; pa.Kw[0] = 1024; pa.Nw[0] = 1024;
  pa.W[1] = (const float*)d_in[3];  pa.Wt[1] = WT2; pa.Kw[1] = 1024; pa.Nw[1] = 512;
  pa.W[2] = (const float*)d_in[5];  pa.Wt[2] = WT3; pa.Kw[2] = 512;  pa.Nw[2] = 256;
  pa.W[3] = (const float*)d_in[7];  pa.Wt[3] = WT4; pa.Kw[3] = 256;  pa.Nw[3] = 256;
  pa.W[4] = (const float*)d_in[10]; pa.Wt[4] = WD1; pa.Kw[4] = 256;  pa.Nw[4] = 256;
  pa.W[5] = (const float*)d_in[12]; pa.Wt[5] = WD2; pa.Kw[5] = 256;  pa.Nw[5] = 512;
  pa.W[6] = (const float*)d_in[14]; pa.Wt[6] = WD3; pa.Kw[6] = 512;  pa.Nw[6] = 1024;
  pa.W[7] = (const float*)d_in[16]; pa.Wt[7] = WD4; pa.Kw[7] = 1024; pa.Nw[7] = 1024;
  int acc = 0;
  for (int w = 0; w < 8; w++) {
    pa.base[w] = acc;
    acc += (pa.Kw[w] >> 5) * (pa.Nw[w] >> 5);
  }
  pa.base[8] = acc;  // 3456
  pa.x = x; pa.xh = xh; pa.E = E; pa.Ehf = Ehf; pa.ek2 = ek2;

  dim3 blk(256);
  prep_k<<<8192 + 3456 + 8, blk, 0, stream>>>(pa);

  // encoder
  gemm8p<0><<<dim3(4, 64), dim3(512), 131072, stream>>>(
      xh, WT1, be1, h1, nullptr, 16384, 1024, 1024, nullptr, nullptr);
  gemm_bt<0, 128, 128><<<dim3(4, 128), blk, 0, stream>>>(
      h1, WT2, be2, h2, nullptr, 16384, 512, 1024, nullptr, nullptr);
  gemm_bt<0, 64, 64><<<dim3(4, 256), blk, 0, stream>>>(
      h2, WT3, be3, h3, nullptr, 16384, 256, 512, nullptr, nullptr);
  gemm_bt<1, 64, 64><<<dim3(4, 256), blk, 0, stream>>>(
      h3, WT4, be4, zhw, zout, 16384, 256, 256, nullptr, nullptr);
  // vector quantizer
  vq_argmin<<<1024, blk, 0, stream>>>(zhw, Ehf, E, ek2, eout, qh, &scal[0]);
  // decoder
  gemm_bt<0, 64, 64><<<dim3(4, 256), blk, 0, stream>>>(
      qh, WD1, bd1, h3, nullptr, 16384, 256, 256, nullptr, nullptr);
  gemm_bt<0, 128, 128><<<dim3(4, 128), blk, 0, stream>>>(
      h3, WD2, bd2, h2, nullptr, 16384, 512, 256, nullptr, nullptr);
  gemm8p<0><<<dim3(4, 64), dim3(512), 131072, stream>>>(
      h2, WD3, bd3, h1, nullptr, 16384, 1024, 512, nullptr, nullptr);
  gemm8p<2><<<dim3(4, 64), dim3(512), 131072, stream>>>(
      h1, WD4, bd4, nullptr, rout, 16384, 1024, 1024, xh, &scal[1]);
  finalize_k<<<1, 1, 0, stream>>>(scal, sout);
}